// Round 6
// baseline (1894.587 us; speedup 1.0000x reference)
//
#include <hip/hip_runtime.h>
#include <cstdint>

typedef unsigned short u16;
typedef __attribute__((ext_vector_type(8))) short short8;
typedef __attribute__((ext_vector_type(4))) short short4v;
typedef __attribute__((ext_vector_type(16))) float floatx16;

__device__ __forceinline__ u16 f2bf(float f) {
    unsigned u = __float_as_uint(f);
    return (u16)((u + 0x7FFFu + ((u >> 16) & 1u)) >> 16);  // RNE
}
__device__ __forceinline__ float bf2f(u16 h) {
    return __uint_as_float(((unsigned)h) << 16);
}

__device__ __forceinline__ void gload16(u16* lds, const u16* g) {
    __builtin_amdgcn_global_load_lds(
        (const __attribute__((address_space(1))) unsigned*)g,
        (__attribute__((address_space(3))) unsigned*)lds,
        16, 0, 0);
}

#define CFENCE asm volatile("" ::: "memory")
#define MFMA32(a, b, c) __builtin_amdgcn_mfma_f32_32x32x16_bf16(a, b, c, 0, 0, 0)

// ---------------- elementwise f32 -> bf16 cast (vectorized) ----------------
__global__ void cast_kernel(const float* __restrict__ in, u16* __restrict__ out, int n4) {
    int stride = gridDim.x * blockDim.x;
    for (int i = blockIdx.x * blockDim.x + threadIdx.x; i < n4; i += stride) {
        float4 v = ((const float4*)in)[i];
        short4v o;
        o[0] = (short)f2bf(v.x);
        o[1] = (short)f2bf(v.y);
        o[2] = (short)f2bf(v.z);
        o[3] = (short)f2bf(v.w);
        ((short4v*)out)[i] = o;
    }
}

// ------------- emb [32000][4096] f32 -> Et [4096][32000] bf16 --------------
__global__ void transpose_cast(const float* __restrict__ E, u16* __restrict__ Et) {
    __shared__ u16 t[32][34];
    int bx = blockIdx.x, by = blockIdx.y;
    int x = threadIdx.x, y = threadIdx.y;
    long long c = (long long)bx * 32 + x;
    long long r0 = (long long)by * 32;
#pragma unroll
    for (int i = y; i < 32; i += 8)
        t[x][i] = f2bf(E[(r0 + i) * 4096 + c]);
    __syncthreads();
    int v = by * 32 + x;
#pragma unroll
    for (int i = y; i < 32; i += 8)
        Et[(long long)(bx * 32 + i) * 32000 + v] = t[i][x];
}

// ---------------- row sums of P (bf16) -> l (f32), deterministic -----------
__global__ void rowsum_kernel(const u16* __restrict__ P, float* __restrict__ l, int V) {
    long long base = (long long)blockIdx.x * V;
    const short8* p8 = (const short8*)(P + base);
    int n8 = V >> 3;
    float s = 0.f;
    for (int c = threadIdx.x; c < n8; c += blockDim.x) {
        short8 v = p8[c];
#pragma unroll
        for (int j = 0; j < 8; ++j) s += bf2f((u16)v[j]);
    }
#pragma unroll
    for (int off = 32; off > 0; off >>= 1) s += __shfl_down(s, off, 64);
    __shared__ float red[4];
    if ((threadIdx.x & 63) == 0) red[threadIdx.x >> 6] = s;
    __syncthreads();
    if (threadIdx.x == 0) l[blockIdx.x] = red[0] + red[1] + red[2] + red[3];
}

// ========= 256x256 NT GEMM, 32x32x16 MFMA, 2-barrier deep pipeline =========
// Schedule identical to R5 (race audit carries over); per-phase contents are
// quadrant (m-half x n-half) = 2 mt x 4 js = 8 MFMA. All LDS read offsets and
// global stage offsets precomputed; t-loop unrolled x2 so LDS bases are
// compile-time. EP=0: store exp(C+bias[col]) bf16. EP=1: C/rowsum[row] f32.

__device__ __forceinline__ short8 ldsAt(const u16* lds0, int base, unsigned off) {
    return *(const short8*)((const char*)lds0 + base + off);
}
__device__ __forceinline__ u16* ldsW(const u16* lds0, int base, int elemOff) {
    return (u16*)((char*)lds0 + base) + elemOff;
}
#define HB(DD, OP, H) ((DD) * 65536 + (OP) * 32768 + (H) * 16384)

template <int EP>
__global__ __launch_bounds__(512, 2)
void gemm32(const u16* __restrict__ A, const u16* __restrict__ B,
            int M, int N, int K,
            const float* __restrict__ bias, u16* __restrict__ Pout,
            const float* __restrict__ rsum, float* __restrict__ Cout) {
    __shared__ u16 lds[2][2][2][128][64];
    const u16* lds0 = &lds[0][0][0][0][0];
    const int tid = threadIdx.x;
    const int w = tid >> 6, lane = tid & 63;
    const int wm = w >> 2, wn = w & 3;
    const int l31 = lane & 31, kh = lane >> 5;
    const int wBase = w * 1024;  // LDS elem offset of this wave's stage rows

    int tm, tn;
    const int nTm = M >> 8;
    if (gridDim.x == 256) {            // GEMM2: 4tm x 8tn per XCD
        const int x = blockIdx.x & 7, wgx = blockIdx.x >> 3;
        tm = (x & 3) * 4 + (wgx & 3);
        tn = (x >> 2) * 8 + (wgx >> 2);
    } else {                           // chunked XCD swizzle, tm-fastest
        const int q = gridDim.x >> 3;
        const int wg = (blockIdx.x & 7) * q + (blockIdx.x >> 3);
        tm = wg % nTm;
        tn = wg / nTm;
    }

    const u16* Abase = A + (long long)tm * 256 * K;
    const u16* Bbase = B + (long long)tn * 256 * K;
    const int NT = K >> 6;

    // ---- precomputed fragment read offsets (bytes within one half-tile) ----
    unsigned offA[2][4], offB[4];
#pragma unroll
    for (int mtl = 0; mtl < 2; ++mtl)
#pragma unroll
        for (int js = 0; js < 4; ++js) {
            int R = wm * 64 + mtl * 32 + l31;
            offA[mtl][js] = (unsigned)(R * 128 + (((js * 2 + kh) ^ ((R >> 1) & 7)) * 16));
        }
#pragma unroll
    for (int js = 0; js < 4; ++js) {
        int R = wn * 32 + l31;
        offB[js] = (unsigned)(R * 128 + (((js * 2 + kh) ^ ((R >> 1) & 7)) * 16));
    }

    // ---- global stage source offsets (32-bit elems; buffers < 4G elems) ----
    auto gOffA = [&](int h, int i, int t) -> unsigned {
        int r = w * 16 + i * 8 + (lane >> 3);
        int gc = (lane & 7) ^ ((r >> 1) & 7);
        int grow = ((r >> 6) << 7) + (h << 6) + (r & 63);
        return (unsigned)(grow * K + t * 64 + gc * 8);
    };
    auto gOffB = [&](int h, int i, int t) -> unsigned {
        int r = w * 16 + i * 8 + (lane >> 3);
        int gc = (lane & 7) ^ ((r >> 1) & 7);
        int grow = ((r >> 5) << 6) + (h << 5) + (r & 31);
        return (unsigned)(grow * K + t * 64 + gc * 8);
    };

    floatx16 acc[4][2] = {};
    short8 af[2][4], bf0[4], bf1[4];

    // ---- prologue: tile0 {A0,B0,B1,A1} + tile1 {A0,B1,A1}; vmcnt(6) ----
#pragma unroll
    for (int i = 0; i < 2; ++i) gload16(ldsW(lds0, HB(0,0,0), wBase + i*512), Abase + gOffA(0,i,0));
#pragma unroll
    for (int i = 0; i < 2; ++i) gload16(ldsW(lds0, HB(0,1,0), wBase + i*512), Bbase + gOffB(0,i,0));
#pragma unroll
    for (int i = 0; i < 2; ++i) gload16(ldsW(lds0, HB(0,1,1), wBase + i*512), Bbase + gOffB(1,i,0));
#pragma unroll
    for (int i = 0; i < 2; ++i) gload16(ldsW(lds0, HB(0,0,1), wBase + i*512), Abase + gOffA(1,i,0));
    if (NT > 1) {
#pragma unroll
        for (int i = 0; i < 2; ++i) gload16(ldsW(lds0, HB(1,0,0), wBase + i*512), Abase + gOffA(0,i,1));
#pragma unroll
        for (int i = 0; i < 2; ++i) gload16(ldsW(lds0, HB(1,1,1), wBase + i*512), Bbase + gOffB(1,i,1));
#pragma unroll
        for (int i = 0; i < 2; ++i) gload16(ldsW(lds0, HB(1,0,1), wBase + i*512), Abase + gOffA(1,i,1));
        asm volatile("s_waitcnt vmcnt(6)" ::: "memory");
    } else {
        asm volatile("s_waitcnt vmcnt(0)" ::: "memory");
    }
    __builtin_amdgcn_s_barrier();
    CFENCE;

    // steady-state stage offsets: Bh0 staged at t+1; Ah0/Bh1/Ah1 at t+2
    unsigned oB0[2] = {gOffB(0, 0, 1), gOffB(0, 1, 1)};
    unsigned oA0[2] = {gOffA(0, 0, 2), gOffA(0, 1, 2)};
    unsigned oB1[2] = {gOffB(1, 0, 2), gOffB(1, 1, 2)};
    unsigned oA1[2] = {gOffA(1, 0, 2), gOffA(1, 1, 2)};

    // preload af <- Ah0(0), bf1 <- Bh1(0)
#pragma unroll
    for (int mtl = 0; mtl < 2; ++mtl)
#pragma unroll
        for (int js = 0; js < 4; ++js)
            af[mtl][js] = ldsAt(lds0, HB(0,0,0), offA[mtl][js]);
#pragma unroll
    for (int js = 0; js < 4; ++js)
        bf1[js] = ldsAt(lds0, HB(0,1,1), offB[js]);

#define TILE_BODY(DD, T)                                                       \
  { const int t = (T);                                                         \
    /* P1: read bf0(t); stage Bh0(t+1); master lgkm guard; MFMA Q(mh0,nh0) */  \
    _Pragma("unroll")                                                          \
    for (int js = 0; js < 4; ++js)                                             \
        bf0[js] = ldsAt(lds0, HB(DD,1,0), offB[js]);                           \
    if (t + 1 < NT) {                                                          \
        gload16(ldsW(lds0, HB(1-DD,1,0), wBase),       Bbase + oB0[0]);        \
        gload16(ldsW(lds0, HB(1-DD,1,0), wBase + 512), Bbase + oB0[1]);        \
    }                                                                          \
    asm volatile("s_waitcnt lgkmcnt(0)" ::: "memory");                         \
    __builtin_amdgcn_sched_barrier(0);                                         \
    __builtin_amdgcn_s_setprio(1);                                             \
    _Pragma("unroll")                                                          \
    for (int mt = 0; mt < 2; ++mt)                                             \
      _Pragma("unroll")                                                        \
      for (int js = 0; js < 4; ++js)                                           \
        acc[mt][0] = MFMA32(af[mt][js], bf0[js], acc[mt][0]);                  \
    __builtin_amdgcn_s_setprio(0);                                             \
    __builtin_amdgcn_s_barrier(); /* B1 */                                     \
    CFENCE;                                                                    \
    /* P2: stage Ah0(t+2),Bh1(t+2); MFMA Q(mh0,nh1); af <- Ah1(t) under */     \
    if (t + 2 < NT) {                                                          \
        gload16(ldsW(lds0, HB(DD,0,0), wBase),       Abase + oA0[0]);          \
        gload16(ldsW(lds0, HB(DD,0,0), wBase + 512), Abase + oA0[1]);          \
        gload16(ldsW(lds0, HB(DD,1,1), wBase),       Bbase + oB1[0]);          \
        gload16(ldsW(lds0, HB(DD,1,1), wBase + 512), Bbase + oB1[1]);          \
    }                                                                          \
    __builtin_amdgcn_s_setprio(1);                                             \
    _Pragma("unroll")                                                          \
    for (int mt = 0; mt < 2; ++mt) {                                           \
      _Pragma("unroll")                                                        \
      for (int js = 0; js < 4; ++js)                                           \
        acc[mt][1] = MFMA32(af[mt][js], bf1[js], acc[mt][1]);                  \
      _Pragma("unroll")                                                        \
      for (int js = 0; js < 4; ++js)                                           \
        af[mt][js] = ldsAt(lds0, HB(DD,0,1), offA[mt][js]);                    \
    }                                                                          \
    __builtin_amdgcn_s_setprio(0);                                             \
    /* P3: MFMA Q(mh1,nh1) */                                                  \
    __builtin_amdgcn_s_setprio(1);                                             \
    _Pragma("unroll")                                                          \
    for (int mt = 0; mt < 2; ++mt)                                             \
      _Pragma("unroll")                                                        \
      for (int js = 0; js < 4; ++js)                                           \
        acc[2 + mt][1] = MFMA32(af[mt][js], bf1[js], acc[2 + mt][1]);          \
    __builtin_amdgcn_s_setprio(0);                                             \
    /* P4: counted vmcnt; B2; stage Ah1(t+2); MFMA Q(mh1,nh0) + prefetch */    \
    if (t + 2 < NT) {                                                          \
        asm volatile("s_waitcnt vmcnt(4)" ::: "memory");                       \
    } else if (t + 1 < NT) {                                                   \
        asm volatile("s_waitcnt vmcnt(0)" ::: "memory");                       \
    }                                                                          \
    __builtin_amdgcn_s_barrier(); /* B2 */                                     \
    CFENCE;                                                                    \
    if (t + 2 < NT) {                                                          \
        gload16(ldsW(lds0, HB(DD,0,1), wBase),       Abase + oA1[0]);          \
        gload16(ldsW(lds0, HB(DD,0,1), wBase + 512), Abase + oA1[1]);          \
    }                                                                          \
    if (t + 1 < NT) {                                                          \
      _Pragma("unroll")                                                        \
      for (int js = 0; js < 4; ++js)                                           \
        bf1[js] = ldsAt(lds0, HB(1-DD,1,1), offB[js]);                         \
      __builtin_amdgcn_s_setprio(1);                                           \
      _Pragma("unroll")                                                        \
      for (int mt = 0; mt < 2; ++mt) {                                         \
        _Pragma("unroll")                                                      \
        for (int js = 0; js < 4; ++js)                                         \
          acc[2 + mt][0] = MFMA32(af[mt][js], bf0[js], acc[2 + mt][0]);        \
        _Pragma("unroll")                                                      \
        for (int js = 0; js < 4; ++js)                                         \
          af[mt][js] = ldsAt(lds0, HB(1-DD,0,0), offA[mt][js]);                \
      }                                                                        \
      __builtin_amdgcn_s_setprio(0);                                           \
    } else {                                                                   \
      __builtin_amdgcn_s_setprio(1);                                           \
      _Pragma("unroll")                                                        \
      for (int mt = 0; mt < 2; ++mt)                                           \
        _Pragma("unroll")                                                      \
        for (int js = 0; js < 4; ++js)                                         \
          acc[2 + mt][0] = MFMA32(af[mt][js], bf0[js], acc[2 + mt][0]);        \
      __builtin_amdgcn_s_setprio(0);                                           \
    }                                                                          \
    _Pragma("unroll")                                                          \
    for (int i = 0; i < 2; ++i) {                                              \
        oB0[i] += 64; oA0[i] += 64; oB1[i] += 64; oA1[i] += 64;                \
    }                                                                          \
    CFENCE;                                                                    \
  }

    for (int tt = 0; tt < NT; tt += 2) {
        TILE_BODY(0, tt);
        TILE_BODY(1, tt + 1);
    }
#undef TILE_BODY

    // ---- epilogue: 32x32 C/D layout col=lane&31, row=(reg&3)+8*(reg>>2)+4*kh
    const int rBase = tm * 256 + wm * 128;
    const int cBase = tn * 256 + wn * 64;
#pragma unroll
    for (int mt = 0; mt < 4; ++mt) {
#pragma unroll
        for (int nt = 0; nt < 2; ++nt) {
            const int col = cBase + nt * 32 + l31;
            if (EP == 0) {
                float bv = bias[col];
#pragma unroll
                for (int reg = 0; reg < 16; ++reg) {
                    int row = rBase + mt * 32 + (reg & 3) + 8 * (reg >> 2) + 4 * kh;
                    Pout[(long long)row * N + col] = f2bf(__expf(acc[mt][nt][reg] + bv));
                }
            } else {
#pragma unroll
                for (int reg = 0; reg < 16; ++reg) {
                    int row = rBase + mt * 32 + (reg & 3) + 8 * (reg >> 2) + 4 * kh;
                    Cout[(long long)row * N + col] = acc[mt][nt][reg] * (1.0f / rsum[row]);
                }
            }
        }
    }
}

extern "C" void kernel_launch(void* const* d_in, const int* in_sizes, int n_in,
                              void* d_out, int out_size, void* d_ws, size_t ws_size,
                              hipStream_t stream) {
    const float* x = (const float*)d_in[0];   // [2,2048,1024]
    const float* W = (const float*)d_in[1];   // [32000,1024]
    const float* b = (const float*)d_in[2];   // [32000]
    const float* E = (const float*)d_in[3];   // [32000,4096]
    float* out = (float*)d_out;               // [2,2048,4096]

    const int M = 4096, K1 = 1024, V = 32000, N2 = 4096;

    char* ws = (char*)d_ws;
    size_t off = 0;
    u16* xb = (u16*)(ws + off); off += (size_t)M * K1 * 2;
    u16* Wb = (u16*)(ws + off); off += (size_t)V * K1 * 2;
    u16* Et = (u16*)(ws + off); off += (size_t)N2 * V * 2;
    u16* P  = (u16*)(ws + off); off += (size_t)M * V * 2;
    float* l = (float*)(ws + off); off += (size_t)M * 4;

    cast_kernel<<<2048, 256, 0, stream>>>(x, xb, M * K1 / 4);
    cast_kernel<<<2048, 256, 0, stream>>>(W, Wb, V * K1 / 4);
    transpose_cast<<<dim3(N2 / 32, V / 32), dim3(32, 8), 0, stream>>>(E, Et);
    // GEMM1: [4096 x 32000 x 1024] -> P = exp(x@W^T + b), bf16
    gemm32<0><<<(M / 256) * (V / 256), 512, 0, stream>>>(xb, Wb, M, V, K1, b, P, nullptr, nullptr);
    rowsum_kernel<<<M, 256, 0, stream>>>(P, l, V);
    // GEMM2: [4096 x 4096 x 32000] -> out = (P/l) @ Et^T, f32
    gemm32<1><<<(M / 256) * (N2 / 256), 512, 0, stream>>>(P, Et, M, N2, V, nullptr, nullptr, l, out);
}

// Round 7
// 1589.918 us; speedup vs baseline: 1.1916x; 1.1916x over previous
//
#include <hip/hip_runtime.h>
#include <cstdint>

typedef unsigned short u16;
typedef __attribute__((ext_vector_type(8))) short short8;
typedef __attribute__((ext_vector_type(4))) short short4v;
typedef __attribute__((ext_vector_type(4))) float floatx4;

__device__ __forceinline__ u16 f2bf(float f) {
    unsigned u = __float_as_uint(f);
    return (u16)((u + 0x7FFFu + ((u >> 16) & 1u)) >> 16);  // RNE
}
__device__ __forceinline__ float bf2f(u16 h) {
    return __uint_as_float(((unsigned)h) << 16);
}

__device__ __forceinline__ void gload16(u16* lds, const u16* g) {
    __builtin_amdgcn_global_load_lds(
        (const __attribute__((address_space(1))) unsigned*)g,
        (__attribute__((address_space(3))) unsigned*)lds,
        16, 0, 0);
}

#define CFENCE asm volatile("" ::: "memory")
#define MFMA16(a, b, c) __builtin_amdgcn_mfma_f32_16x16x32_bf16(a, b, c, 0, 0, 0)

// ---------------- elementwise f32 -> bf16 cast (vectorized) ----------------
__global__ void cast_kernel(const float* __restrict__ in, u16* __restrict__ out, int n4) {
    int stride = gridDim.x * blockDim.x;
    for (int i = blockIdx.x * blockDim.x + threadIdx.x; i < n4; i += stride) {
        float4 v = ((const float4*)in)[i];
        short4v o;
        o[0] = (short)f2bf(v.x);
        o[1] = (short)f2bf(v.y);
        o[2] = (short)f2bf(v.z);
        o[3] = (short)f2bf(v.w);
        ((short4v*)out)[i] = o;
    }
}

// ------------- emb [32000][4096] f32 -> Et [4096][32000] bf16 --------------
__global__ void transpose_cast(const float* __restrict__ E, u16* __restrict__ Et) {
    __shared__ u16 t[32][34];
    int bx = blockIdx.x, by = blockIdx.y;
    int x = threadIdx.x, y = threadIdx.y;
    long long c = (long long)bx * 32 + x;
    long long r0 = (long long)by * 32;
#pragma unroll
    for (int i = y; i < 32; i += 8)
        t[x][i] = f2bf(E[(r0 + i) * 4096 + c]);
    __syncthreads();
    int v = by * 32 + x;
#pragma unroll
    for (int i = y; i < 32; i += 8)
        Et[(long long)(bx * 32 + i) * 32000 + v] = t[i][x];
}

// ---------------- row sums of P (bf16) -> l (f32), deterministic -----------
__global__ void rowsum_kernel(const u16* __restrict__ P, float* __restrict__ l, int V) {
    long long base = (long long)blockIdx.x * V;
    const short8* p8 = (const short8*)(P + base);
    int n8 = V >> 3;
    float s = 0.f;
    for (int c = threadIdx.x; c < n8; c += blockDim.x) {
        short8 v = p8[c];
#pragma unroll
        for (int j = 0; j < 8; ++j) s += bf2f((u16)v[j]);
    }
#pragma unroll
    for (int off = 32; off > 0; off >>= 1) s += __shfl_down(s, off, 64);
    __shared__ float red[4];
    if ((threadIdx.x & 63) == 0) red[threadIdx.x >> 6] = s;
    __syncthreads();
    if (threadIdx.x == 0) l[blockIdx.x] = red[0] + red[1] + red[2] + red[3];
}

// == 256x256 NT GEMM, 16x16x32 MFMA (8 indep acc chains), hoisted addresses ==
// Schedule = R5 (2-barrier, race audit carries over). Address machinery = R6:
// 12 precomputed ds_read byte offsets, 8 precomputed global stage offsets
// advanced by +64 elems/tile, t-loop unrolled x2 -> compile-time LDS bases.
// EP=0: store exp(C+bias[col]) bf16.  EP=1: store C/rowsum[row] f32.

__device__ __forceinline__ short8 ldsAt(const u16* lds0, int base, unsigned off) {
    return *(const short8*)((const char*)lds0 + base + off);
}
__device__ __forceinline__ u16* ldsW(const u16* lds0, int base, int elemOff) {
    return (u16*)((char*)lds0 + base) + elemOff;
}
#define HB(DD, OP, H) ((DD) * 65536 + (OP) * 32768 + (H) * 16384)

template <int EP>
__global__ __launch_bounds__(512, 2)
void gemm8p(const u16* __restrict__ A, const u16* __restrict__ B,
            int M, int N, int K,
            const float* __restrict__ bias, u16* __restrict__ Pout,
            const float* __restrict__ rsum, float* __restrict__ Cout) {
    __shared__ u16 lds[2][2][2][128][64];
    const u16* lds0 = &lds[0][0][0][0][0];
    const int tid = threadIdx.x;
    const int w = tid >> 6, lane = tid & 63;
    const int wm = w >> 2, wn = w & 3;
    const int fRow = lane & 15, fC = lane >> 4;
    const int wBase = w * 1024;  // this wave's stage region (elems)

    int tm, tn;
    const int nTm = M >> 8;
    if (gridDim.x == 256) {            // GEMM2: 4tm x 8tn per XCD
        const int x = blockIdx.x & 7, wgx = blockIdx.x >> 3;
        tm = (x & 3) * 4 + (wgx & 3);
        tn = (x >> 2) * 8 + (wgx >> 2);
    } else {                           // chunked XCD swizzle, tm-fastest
        const int q = gridDim.x >> 3;
        const int wg = (blockIdx.x & 7) * q + (blockIdx.x >> 3);
        tm = wg % nTm;
        tn = wg / nTm;
    }

    const u16* Abase = A + (long long)tm * 256 * K;
    const u16* Bbase = B + (long long)tn * 256 * K;
    const int NT = K >> 6;

    // ---- precomputed fragment read byte-offsets (within one half-tile) ----
    unsigned offA[4][2], offB[2][2];
#pragma unroll
    for (int m = 0; m < 4; ++m)
#pragma unroll
        for (int kk = 0; kk < 2; ++kk) {
            int R = wm * 64 + m * 16 + fRow;
            offA[m][kk] = (unsigned)(R * 128 + (((kk * 4 + fC) ^ ((R >> 1) & 7)) * 16));
        }
#pragma unroll
    for (int n = 0; n < 2; ++n)
#pragma unroll
        for (int kk = 0; kk < 2; ++kk) {
            int R = wn * 32 + n * 16 + fRow;
            offB[n][kk] = (unsigned)(R * 128 + (((kk * 4 + fC) ^ ((R >> 1) & 7)) * 16));
        }

    // ---- global stage source offsets (elems; buffers < 4G elems) ----
    auto gOffA = [&](int h, int i, int t) -> unsigned {
        int r = w * 16 + i * 8 + (lane >> 3);
        int gc = (lane & 7) ^ ((r >> 1) & 7);
        int grow = ((r >> 6) << 7) + (h << 6) + (r & 63);
        return (unsigned)(grow * K + t * 64 + gc * 8);
    };
    auto gOffB = [&](int h, int i, int t) -> unsigned {
        int r = w * 16 + i * 8 + (lane >> 3);
        int gc = (lane & 7) ^ ((r >> 1) & 7);
        int grow = ((r >> 5) << 6) + (h << 5) + (r & 31);
        return (unsigned)(grow * K + t * 64 + gc * 8);
    };

    floatx4 acc[8][4] = {};
    short8 af[4][2], bf0[2][2], bf1[2][2];

    // ---- prologue: tile0 {A0,B0,B1,A1} + tile1 {A0,B1,A1}; vmcnt(6) ----
#pragma unroll
    for (int i = 0; i < 2; ++i) gload16(ldsW(lds0, HB(0,0,0), wBase + i*512), Abase + gOffA(0,i,0));
#pragma unroll
    for (int i = 0; i < 2; ++i) gload16(ldsW(lds0, HB(0,1,0), wBase + i*512), Bbase + gOffB(0,i,0));
#pragma unroll
    for (int i = 0; i < 2; ++i) gload16(ldsW(lds0, HB(0,1,1), wBase + i*512), Bbase + gOffB(1,i,0));
#pragma unroll
    for (int i = 0; i < 2; ++i) gload16(ldsW(lds0, HB(0,0,1), wBase + i*512), Abase + gOffA(1,i,0));
    if (NT > 1) {
#pragma unroll
        for (int i = 0; i < 2; ++i) gload16(ldsW(lds0, HB(1,0,0), wBase + i*512), Abase + gOffA(0,i,1));
#pragma unroll
        for (int i = 0; i < 2; ++i) gload16(ldsW(lds0, HB(1,1,1), wBase + i*512), Bbase + gOffB(1,i,1));
#pragma unroll
        for (int i = 0; i < 2; ++i) gload16(ldsW(lds0, HB(1,0,1), wBase + i*512), Abase + gOffA(1,i,1));
        asm volatile("s_waitcnt vmcnt(6)" ::: "memory");
    } else {
        asm volatile("s_waitcnt vmcnt(0)" ::: "memory");
    }
    __builtin_amdgcn_s_barrier();
    CFENCE;

    // steady-state stage offsets: Bh0 staged at t+1; Ah0/Bh1/Ah1 at t+2
    unsigned oB0[2] = {gOffB(0, 0, 1), gOffB(0, 1, 1)};
    unsigned oA0[2] = {gOffA(0, 0, 2), gOffA(0, 1, 2)};
    unsigned oB1[2] = {gOffB(1, 0, 2), gOffB(1, 1, 2)};
    unsigned oA1[2] = {gOffA(1, 0, 2), gOffA(1, 1, 2)};

    // preload af <- Ah0(0), bf1 <- Bh1(0)
#pragma unroll
    for (int m = 0; m < 4; ++m)
#pragma unroll
        for (int kk = 0; kk < 2; ++kk)
            af[m][kk] = ldsAt(lds0, HB(0,0,0), offA[m][kk]);
#pragma unroll
    for (int n = 0; n < 2; ++n)
#pragma unroll
        for (int kk = 0; kk < 2; ++kk)
            bf1[n][kk] = ldsAt(lds0, HB(0,1,1), offB[n][kk]);

#define TILE_BODY(DD, T)                                                       \
  { const int t = (T);                                                         \
    /* P1: read bf0(t); stage Bh0(t+1); master lgkm guard; MFMA Q(0,0) */      \
    _Pragma("unroll")                                                          \
    for (int n = 0; n < 2; ++n)                                                \
      _Pragma("unroll")                                                        \
      for (int kk = 0; kk < 2; ++kk)                                           \
        bf0[n][kk] = ldsAt(lds0, HB(DD,1,0), offB[n][kk]);                     \
    if (t + 1 < NT) {                                                          \
        gload16(ldsW(lds0, HB(1-DD,1,0), wBase),       Bbase + oB0[0]);        \
        gload16(ldsW(lds0, HB(1-DD,1,0), wBase + 512), Bbase + oB0[1]);        \
    }                                                                          \
    asm volatile("s_waitcnt lgkmcnt(0)" ::: "memory");                         \
    __builtin_amdgcn_sched_barrier(0);                                         \
    __builtin_amdgcn_s_setprio(1);                                             \
    _Pragma("unroll")                                                          \
    for (int m = 0; m < 4; ++m)                                                \
      _Pragma("unroll")                                                        \
      for (int n = 0; n < 2; ++n)                                              \
        _Pragma("unroll")                                                      \
        for (int kk = 0; kk < 2; ++kk)                                         \
          acc[m][n] = MFMA16(af[m][kk], bf0[n][kk], acc[m][n]);                \
    __builtin_amdgcn_s_setprio(0);                                             \
    __builtin_amdgcn_s_barrier(); /* B1 */                                     \
    CFENCE;                                                                    \
    /* P2: stage Ah0(t+2),Bh1(t+2); MFMA Q(0,1); af <- Ah1(t) under */         \
    if (t + 2 < NT) {                                                          \
        gload16(ldsW(lds0, HB(DD,0,0), wBase),       Abase + oA0[0]);          \
        gload16(ldsW(lds0, HB(DD,0,0), wBase + 512), Abase + oA0[1]);          \
        gload16(ldsW(lds0, HB(DD,1,1), wBase),       Bbase + oB1[0]);          \
        gload16(ldsW(lds0, HB(DD,1,1), wBase + 512), Bbase + oB1[1]);          \
    }                                                                          \
    __builtin_amdgcn_s_setprio(1);                                             \
    _Pragma("unroll")                                                          \
    for (int m = 0; m < 4; ++m) {                                              \
      _Pragma("unroll")                                                        \
      for (int n = 0; n < 2; ++n)                                              \
        _Pragma("unroll")                                                      \
        for (int kk = 0; kk < 2; ++kk)                                         \
          acc[m][2 + n] = MFMA16(af[m][kk], bf1[n][kk], acc[m][2 + n]);        \
      _Pragma("unroll")                                                        \
      for (int kk = 0; kk < 2; ++kk)                                           \
        af[m][kk] = ldsAt(lds0, HB(DD,0,1), offA[m][kk]);                      \
    }                                                                          \
    __builtin_amdgcn_s_setprio(0);                                             \
    /* P3: MFMA Q(1,1) */                                                      \
    __builtin_amdgcn_s_setprio(1);                                             \
    _Pragma("unroll")                                                          \
    for (int m = 0; m < 4; ++m)                                                \
      _Pragma("unroll")                                                        \
      for (int n = 0; n < 2; ++n)                                              \
        _Pragma("unroll")                                                      \
        for (int kk = 0; kk < 2; ++kk)                                         \
          acc[4 + m][2 + n] = MFMA16(af[m][kk], bf1[n][kk], acc[4 + m][2 + n]);\
    __builtin_amdgcn_s_setprio(0);                                             \
    /* P4: counted vmcnt; B2; stage Ah1(t+2); MFMA Q(1,0) + prefetch */        \
    if (t + 2 < NT) {                                                          \
        asm volatile("s_waitcnt vmcnt(4)" ::: "memory");                       \
    } else if (t + 1 < NT) {                                                   \
        asm volatile("s_waitcnt vmcnt(0)" ::: "memory");                       \
    }                                                                          \
    __builtin_amdgcn_s_barrier(); /* B2 */                                     \
    CFENCE;                                                                    \
    if (t + 2 < NT) {                                                          \
        gload16(ldsW(lds0, HB(DD,0,1), wBase),       Abase + oA1[0]);          \
        gload16(ldsW(lds0, HB(DD,0,1), wBase + 512), Abase + oA1[1]);          \
    }                                                                          \
    if (t + 1 < NT) {                                                          \
      _Pragma("unroll")                                                        \
      for (int n = 0; n < 2; ++n)                                              \
        _Pragma("unroll")                                                      \
        for (int kk = 0; kk < 2; ++kk)                                         \
          bf1[n][kk] = ldsAt(lds0, HB(1-DD,1,1), offB[n][kk]);                 \
      __builtin_amdgcn_s_setprio(1);                                           \
      _Pragma("unroll")                                                        \
      for (int m = 0; m < 4; ++m) {                                            \
        _Pragma("unroll")                                                      \
        for (int n = 0; n < 2; ++n)                                            \
          _Pragma("unroll")                                                    \
          for (int kk = 0; kk < 2; ++kk)                                       \
            acc[4 + m][n] = MFMA16(af[m][kk], bf0[n][kk], acc[4 + m][n]);      \
        _Pragma("unroll")                                                      \
        for (int kk = 0; kk < 2; ++kk)                                         \
          af[m][kk] = ldsAt(lds0, HB(1-DD,0,0), offA[m][kk]);                  \
      }                                                                        \
      __builtin_amdgcn_s_setprio(0);                                           \
    } else {                                                                   \
      __builtin_amdgcn_s_setprio(1);                                           \
      _Pragma("unroll")                                                        \
      for (int m = 0; m < 4; ++m)                                              \
        _Pragma("unroll")                                                      \
        for (int n = 0; n < 2; ++n)                                            \
          _Pragma("unroll")                                                    \
          for (int kk = 0; kk < 2; ++kk)                                       \
            acc[4 + m][n] = MFMA16(af[m][kk], bf0[n][kk], acc[4 + m][n]);      \
      __builtin_amdgcn_s_setprio(0);                                           \
    }                                                                          \
    _Pragma("unroll")                                                          \
    for (int i = 0; i < 2; ++i) {                                              \
        oB0[i] += 64; oA0[i] += 64; oB1[i] += 64; oA1[i] += 64;                \
    }                                                                          \
    CFENCE;                                                                    \
  }

    for (int tt = 0; tt < NT; tt += 2) {
        TILE_BODY(0, tt);
        TILE_BODY(1, tt + 1);
    }
#undef TILE_BODY

    // ---- epilogue: C/D layout col=lane&15, row=(lane>>4)*4+reg ----
    const int rBase = tm * 256 + wm * 128;
    const int cBase = tn * 256 + wn * 64;
    const int rOff = (lane >> 4) * 4;
    const int cOff = lane & 15;
#pragma unroll
    for (int m = 0; m < 8; ++m) {
#pragma unroll
        for (int n = 0; n < 4; ++n) {
            const int col = cBase + n * 16 + cOff;
            if (EP == 0) {
                float bv = bias[col];
#pragma unroll
                for (int r = 0; r < 4; ++r) {
                    int row = rBase + m * 16 + rOff + r;
                    Pout[(long long)row * N + col] = f2bf(__expf(acc[m][n][r] + bv));
                }
            } else {
#pragma unroll
                for (int r = 0; r < 4; ++r) {
                    int row = rBase + m * 16 + rOff + r;
                    Cout[(long long)row * N + col] = acc[m][n][r] * (1.0f / rsum[row]);
                }
            }
        }
    }
}

extern "C" void kernel_launch(void* const* d_in, const int* in_sizes, int n_in,
                              void* d_out, int out_size, void* d_ws, size_t ws_size,
                              hipStream_t stream) {
    const float* x = (const float*)d_in[0];   // [2,2048,1024]
    const float* W = (const float*)d_in[1];   // [32000,1024]
    const float* b = (const float*)d_in[2];   // [32000]
    const float* E = (const float*)d_in[3];   // [32000,4096]
    float* out = (float*)d_out;               // [2,2048,4096]

    const int M = 4096, K1 = 1024, V = 32000, N2 = 4096;

    char* ws = (char*)d_ws;
    size_t off = 0;
    u16* xb = (u16*)(ws + off); off += (size_t)M * K1 * 2;
    u16* Wb = (u16*)(ws + off); off += (size_t)V * K1 * 2;
    u16* Et = (u16*)(ws + off); off += (size_t)N2 * V * 2;
    u16* P  = (u16*)(ws + off); off += (size_t)M * V * 2;
    float* l = (float*)(ws + off); off += (size_t)M * 4;

    cast_kernel<<<2048, 256, 0, stream>>>(x, xb, M * K1 / 4);
    cast_kernel<<<2048, 256, 0, stream>>>(W, Wb, V * K1 / 4);
    transpose_cast<<<dim3(N2 / 32, V / 32), dim3(32, 8), 0, stream>>>(E, Et);
    // GEMM1: [4096 x 32000 x 1024] -> P = exp(x@W^T + b), bf16
    gemm8p<0><<<(M / 256) * (V / 256), 512, 0, stream>>>(xb, Wb, M, V, K1, b, P, nullptr, nullptr);
    rowsum_kernel<<<M, 256, 0, stream>>>(P, l, V);
    // GEMM2: [4096 x 4096 x 32000] -> out = (P/l) @ Et^T, f32
    gemm8p<1><<<(M / 256) * (N2 / 256), 512, 0, stream>>>(P, Et, M, N2, V, nullptr, nullptr, l, out);
}

// Round 8
// 1391.115 us; speedup vs baseline: 1.3619x; 1.1429x over previous
//
#include <hip/hip_runtime.h>
#include <cstdint>

typedef unsigned short u16;
typedef __attribute__((ext_vector_type(8))) short short8;
typedef __attribute__((ext_vector_type(4))) short short4v;
typedef __attribute__((ext_vector_type(4))) float floatx4;

__device__ __forceinline__ u16 f2bf(float f) {
    unsigned u = __float_as_uint(f);
    return (u16)((u + 0x7FFFu + ((u >> 16) & 1u)) >> 16);  // RNE
}
__device__ __forceinline__ float bf2f(u16 h) {
    return __uint_as_float(((unsigned)h) << 16);
}

__device__ __forceinline__ void gload16(u16* lds, const u16* g) {
    __builtin_amdgcn_global_load_lds(
        (const __attribute__((address_space(1))) unsigned*)g,
        (__attribute__((address_space(3))) unsigned*)lds,
        16, 0, 0);
}

#define CFENCE asm volatile("" ::: "memory")
#define MFMA16(a, b, c) __builtin_amdgcn_mfma_f32_16x16x32_bf16(a, b, c, 0, 0, 0)

// ---------------- elementwise f32 -> bf16 cast (vectorized) ----------------
__global__ void cast_kernel(const float* __restrict__ in, u16* __restrict__ out, int n4) {
    int stride = gridDim.x * blockDim.x;
    for (int i = blockIdx.x * blockDim.x + threadIdx.x; i < n4; i += stride) {
        float4 v = ((const float4*)in)[i];
        short4v o;
        o[0] = (short)f2bf(v.x);
        o[1] = (short)f2bf(v.y);
        o[2] = (short)f2bf(v.z);
        o[3] = (short)f2bf(v.w);
        ((short4v*)out)[i] = o;
    }
}

// ------------- emb [32000][4096] f32 -> Et [4096][32000] bf16 --------------
__global__ void transpose_cast(const float* __restrict__ E, u16* __restrict__ Et) {
    __shared__ u16 t[32][34];
    int bx = blockIdx.x, by = blockIdx.y;
    int x = threadIdx.x, y = threadIdx.y;
    long long c = (long long)bx * 32 + x;
    long long r0 = (long long)by * 32;
#pragma unroll
    for (int i = y; i < 32; i += 8)
        t[x][i] = f2bf(E[(r0 + i) * 4096 + c]);
    __syncthreads();
    int v = by * 32 + x;
#pragma unroll
    for (int i = y; i < 32; i += 8)
        Et[(long long)(bx * 32 + i) * 32000 + v] = t[i][x];
}

// ---------------- row sums of P (bf16) -> l (f32), deterministic -----------
__global__ void rowsum_kernel(const u16* __restrict__ P, float* __restrict__ l, int V) {
    long long base = (long long)blockIdx.x * V;
    const short8* p8 = (const short8*)(P + base);
    int n8 = V >> 3;
    float s = 0.f;
    for (int c = threadIdx.x; c < n8; c += blockDim.x) {
        short8 v = p8[c];
#pragma unroll
        for (int j = 0; j < 8; ++j) s += bf2f((u16)v[j]);
    }
#pragma unroll
    for (int off = 32; off > 0; off >>= 1) s += __shfl_down(s, off, 64);
    __shared__ float red[4];
    if ((threadIdx.x & 63) == 0) red[threadIdx.x >> 6] = s;
    __syncthreads();
    if (threadIdx.x == 0) l[blockIdx.x] = red[0] + red[1] + red[2] + red[3];
}

// ============ 256x256 NT GEMM, 2-barrier deep-pipelined schedule ===========
// R5 schedule verbatim (855us-verified). Hoisting redone with ARRAY-TYPED
// LDS bases (proven ds_read codegen) + precomputed element offsets, and
// precomputed global stage pointers advanced +=64/tile. No char* aliasing.
// Hazard audit = R5 (B1 after Q(0,0); vmcnt(4)+B2 at P4; master lgkm at P1).
// EP=0: store exp(C+bias[col]) bf16.  EP=1: store C/rowsum[row] f32.

template <int EP>
__global__ __launch_bounds__(512, 2)
void gemm8p(const u16* __restrict__ A, const u16* __restrict__ B,
            int M, int N, int K,
            const float* __restrict__ bias, u16* __restrict__ Pout,
            const float* __restrict__ rsum, float* __restrict__ Cout) {
    __shared__ u16 lds[2][2][2][128][64];
    const int tid = threadIdx.x;
    const int w = tid >> 6, lane = tid & 63;
    const int wm = w >> 2, wn = w & 3;
    const int fRow = lane & 15, fC = lane >> 4;
    const int wBase = w * 1024;  // this wave's stage region (elems)

    int tm, tn;
    const int nTm = M >> 8;
    if (gridDim.x == 256) {            // GEMM2: 4tm x 8tn per XCD
        const int x = blockIdx.x & 7, wgx = blockIdx.x >> 3;
        tm = (x & 3) * 4 + (wgx & 3);
        tn = (x >> 2) * 8 + (wgx >> 2);
    } else {                           // chunked XCD swizzle, tm-fastest
        const int q = gridDim.x >> 3;
        const int wg = (blockIdx.x & 7) * q + (blockIdx.x >> 3);
        tm = wg % nTm;
        tn = wg / nTm;
    }

    const u16* Abase = A + (long long)tm * 256 * K;
    const u16* Bbase = B + (long long)tn * 256 * K;
    const int NT = K >> 6;

    // ---- precomputed fragment read ELEMENT offsets (within a half-tile) ----
    unsigned offA[4][2], offB[2][2];
#pragma unroll
    for (int m = 0; m < 4; ++m)
#pragma unroll
        for (int kk = 0; kk < 2; ++kk) {
            int R = wm * 64 + m * 16 + fRow;
            offA[m][kk] = (unsigned)(R * 64 + (((kk * 4 + fC) ^ ((R >> 1) & 7)) * 8));
        }
#pragma unroll
    for (int n = 0; n < 2; ++n)
#pragma unroll
        for (int kk = 0; kk < 2; ++kk) {
            int R = wn * 32 + n * 16 + fRow;
            offB[n][kk] = (unsigned)(R * 64 + (((kk * 4 + fC) ^ ((R >> 1) & 7)) * 8));
        }

    // ---- precomputed global stage source pointers (advanced +=64/tile) ----
    const u16 *pA0[2], *pA1[2], *pB0[2], *pB1[2];
#pragma unroll
    for (int i = 0; i < 2; ++i) {
        int r = w * 16 + i * 8 + (lane >> 3);
        int gcs = (lane & 7) ^ ((r >> 1) & 7);
        long long rowA = ((r >> 6) << 7) + (r & 63);
        long long rowB = ((r >> 5) << 6) + (r & 31);
        pA0[i] = Abase + rowA * K + gcs * 8;
        pA1[i] = Abase + (rowA + 64) * K + gcs * 8;
        pB0[i] = Bbase + rowB * K + gcs * 8;
        pB1[i] = Bbase + (rowB + 32) * K + gcs * 8;
    }

    floatx4 acc[8][4] = {};
    short8 af[4][2], bf0[2][2], bf1[2][2];

    // ---- prologue: tile0 {A0,B0,B1,A1} + tile1 {A0,B1,A1}; vmcnt(6) ----
#pragma unroll
    for (int i = 0; i < 2; ++i) gload16(&lds[0][0][0][0][0] + wBase + i * 512, pA0[i]);
#pragma unroll
    for (int i = 0; i < 2; ++i) gload16(&lds[0][1][0][0][0] + wBase + i * 512, pB0[i]);
#pragma unroll
    for (int i = 0; i < 2; ++i) gload16(&lds[0][1][1][0][0] + wBase + i * 512, pB1[i]);
#pragma unroll
    for (int i = 0; i < 2; ++i) gload16(&lds[0][0][1][0][0] + wBase + i * 512, pA1[i]);
    if (NT > 1) {
#pragma unroll
        for (int i = 0; i < 2; ++i) gload16(&lds[1][0][0][0][0] + wBase + i * 512, pA0[i] + 64);
#pragma unroll
        for (int i = 0; i < 2; ++i) gload16(&lds[1][1][1][0][0] + wBase + i * 512, pB1[i] + 64);
#pragma unroll
        for (int i = 0; i < 2; ++i) gload16(&lds[1][0][1][0][0] + wBase + i * 512, pA1[i] + 64);
        asm volatile("s_waitcnt vmcnt(6)" ::: "memory");
    } else {
        asm volatile("s_waitcnt vmcnt(0)" ::: "memory");
    }
    __builtin_amdgcn_s_barrier();
    CFENCE;

    // steady-state: at tile t, pB0 -> Bh0(t+1); pA0/pB1/pA1 -> (t+2)
#pragma unroll
    for (int i = 0; i < 2; ++i) {
        pB0[i] += 64;
        pA0[i] += 128;
        pB1[i] += 128;
        pA1[i] += 128;
    }

    // preload af <- Ah0(0), bf1 <- Bh1(0)
#pragma unroll
    for (int m = 0; m < 4; ++m)
#pragma unroll
        for (int kk = 0; kk < 2; ++kk)
            af[m][kk] = *(const short8*)(&lds[0][0][0][0][0] + offA[m][kk]);
#pragma unroll
    for (int n = 0; n < 2; ++n)
#pragma unroll
        for (int kk = 0; kk < 2; ++kk)
            bf1[n][kk] = *(const short8*)(&lds[0][1][1][0][0] + offB[n][kk]);

    for (int t = 0; t < NT; ++t) {
        const int d = t & 1;

        // ---------------- P1 ----------------
#pragma unroll
        for (int n = 0; n < 2; ++n)
#pragma unroll
            for (int kk = 0; kk < 2; ++kk)
                bf0[n][kk] = *(const short8*)(&lds[d][1][0][0][0] + offB[n][kk]);
        if (t + 1 < NT) {
            gload16(&lds[d ^ 1][1][0][0][0] + wBase, pB0[0]);
            gload16(&lds[d ^ 1][1][0][0][0] + wBase + 512, pB0[1]);
        }
        asm volatile("s_waitcnt lgkmcnt(0)" ::: "memory");
        __builtin_amdgcn_sched_barrier(0);
        __builtin_amdgcn_s_setprio(1);
#pragma unroll
        for (int m = 0; m < 4; ++m)
#pragma unroll
            for (int n = 0; n < 2; ++n)
#pragma unroll
                for (int kk = 0; kk < 2; ++kk)
                    acc[m][n] = MFMA16(af[m][kk], bf0[n][kk], acc[m][n]);
        __builtin_amdgcn_s_setprio(0);
        __builtin_amdgcn_s_barrier();   // B1
        CFENCE;

        // ---------------- P2 ----------------
        if (t + 2 < NT) {
            gload16(&lds[d][0][0][0][0] + wBase, pA0[0]);
            gload16(&lds[d][0][0][0][0] + wBase + 512, pA0[1]);
            gload16(&lds[d][1][1][0][0] + wBase, pB1[0]);
            gload16(&lds[d][1][1][0][0] + wBase + 512, pB1[1]);
        }
        __builtin_amdgcn_s_setprio(1);
#pragma unroll
        for (int m = 0; m < 4; ++m) {
#pragma unroll
            for (int n = 0; n < 2; ++n)
#pragma unroll
                for (int kk = 0; kk < 2; ++kk)
                    acc[m][2 + n] = MFMA16(af[m][kk], bf1[n][kk], acc[m][2 + n]);
            // af[m] dead for Q(0,1): reload with A-half1(t) under the cluster
#pragma unroll
            for (int kk = 0; kk < 2; ++kk)
                af[m][kk] = *(const short8*)(&lds[d][0][1][0][0] + offA[m][kk]);
        }
        __builtin_amdgcn_s_setprio(0);

        // ---------------- P3 ----------------
        __builtin_amdgcn_s_setprio(1);
#pragma unroll
        for (int m = 0; m < 4; ++m)
#pragma unroll
            for (int n = 0; n < 2; ++n)
#pragma unroll
                for (int kk = 0; kk < 2; ++kk)
                    acc[4 + m][2 + n] = MFMA16(af[m][kk], bf1[n][kk], acc[4 + m][2 + n]);
        __builtin_amdgcn_s_setprio(0);

        // ---------------- P4 ----------------
        if (t + 2 < NT) {
            asm volatile("s_waitcnt vmcnt(4)" ::: "memory");
        } else if (t + 1 < NT) {
            asm volatile("s_waitcnt vmcnt(0)" ::: "memory");
        }
        __builtin_amdgcn_s_barrier();   // B2
        CFENCE;
        if (t + 2 < NT) {
            gload16(&lds[d][0][1][0][0] + wBase, pA1[0]);
            gload16(&lds[d][0][1][0][0] + wBase + 512, pA1[1]);
        }
        if (t + 1 < NT) {
            // prefetch bf1(t+1) at cluster start (bf1 dead after P3)
#pragma unroll
            for (int n = 0; n < 2; ++n)
#pragma unroll
                for (int kk = 0; kk < 2; ++kk)
                    bf1[n][kk] = *(const short8*)(&lds[d ^ 1][1][1][0][0] + offB[n][kk]);
            __builtin_amdgcn_s_setprio(1);
#pragma unroll
            for (int m = 0; m < 4; ++m) {
#pragma unroll
                for (int n = 0; n < 2; ++n)
#pragma unroll
                    for (int kk = 0; kk < 2; ++kk)
                        acc[4 + m][n] = MFMA16(af[m][kk], bf0[n][kk], acc[4 + m][n]);
                // af[m] dead: reload with A-half0(t+1) under the cluster
#pragma unroll
                for (int kk = 0; kk < 2; ++kk)
                    af[m][kk] = *(const short8*)(&lds[d ^ 1][0][0][0][0] + offA[m][kk]);
            }
            __builtin_amdgcn_s_setprio(0);
        } else {
            __builtin_amdgcn_s_setprio(1);
#pragma unroll
            for (int m = 0; m < 4; ++m)
#pragma unroll
                for (int n = 0; n < 2; ++n)
#pragma unroll
                    for (int kk = 0; kk < 2; ++kk)
                        acc[4 + m][n] = MFMA16(af[m][kk], bf0[n][kk], acc[4 + m][n]);
            __builtin_amdgcn_s_setprio(0);
        }
#pragma unroll
        for (int i = 0; i < 2; ++i) {
            pB0[i] += 64;
            pA0[i] += 64;
            pB1[i] += 64;
            pA1[i] += 64;
        }
        CFENCE;
    }

    // ---- epilogue: C/D layout col=lane&15, row=(lane>>4)*4+reg ----
    const int rBase = tm * 256 + wm * 128;
    const int cBase = tn * 256 + wn * 64;
    const int rOff = (lane >> 4) * 4;
    const int cOff = lane & 15;
#pragma unroll
    for (int m = 0; m < 8; ++m) {
#pragma unroll
        for (int n = 0; n < 4; ++n) {
            const int col = cBase + n * 16 + cOff;
            if (EP == 0) {
                float bv = bias[col];
#pragma unroll
                for (int r = 0; r < 4; ++r) {
                    int row = rBase + m * 16 + rOff + r;
                    Pout[(long long)row * N + col] = f2bf(__expf(acc[m][n][r] + bv));
                }
            } else {
#pragma unroll
                for (int r = 0; r < 4; ++r) {
                    int row = rBase + m * 16 + rOff + r;
                    Cout[(long long)row * N + col] = acc[m][n][r] * (1.0f / rsum[row]);
                }
            }
        }
    }
}

extern "C" void kernel_launch(void* const* d_in, const int* in_sizes, int n_in,
                              void* d_out, int out_size, void* d_ws, size_t ws_size,
                              hipStream_t stream) {
    const float* x = (const float*)d_in[0];   // [2,2048,1024]
    const float* W = (const float*)d_in[1];   // [32000,1024]
    const float* b = (const float*)d_in[2];   // [32000]
    const float* E = (const float*)d_in[3];   // [32000,4096]
    float* out = (float*)d_out;               // [2,2048,4096]

    const int M = 4096, K1 = 1024, V = 32000, N2 = 4096;

    char* ws = (char*)d_ws;
    size_t off = 0;
    u16* xb = (u16*)(ws + off); off += (size_t)M * K1 * 2;
    u16* Wb = (u16*)(ws + off); off += (size_t)V * K1 * 2;
    u16* Et = (u16*)(ws + off); off += (size_t)N2 * V * 2;
    u16* P  = (u16*)(ws + off); off += (size_t)M * V * 2;
    float* l = (float*)(ws + off); off += (size_t)M * 4;

    cast_kernel<<<2048, 256, 0, stream>>>(x, xb, M * K1 / 4);
    cast_kernel<<<2048, 256, 0, stream>>>(W, Wb, V * K1 / 4);
    transpose_cast<<<dim3(N2 / 32, V / 32), dim3(32, 8), 0, stream>>>(E, Et);
    // GEMM1: [4096 x 32000 x 1024] -> P = exp(x@W^T + b), bf16
    gemm8p<0><<<(M / 256) * (V / 256), 512, 0, stream>>>(xb, Wb, M, V, K1, b, P, nullptr, nullptr);
    rowsum_kernel<<<M, 256, 0, stream>>>(P, l, V);
    // GEMM2: [4096 x 4096 x 32000] -> out = (P/l) @ Et^T, f32
    gemm8p<1><<<(M / 256) * (N2 / 256), 512, 0, stream>>>(P, Et, M, N2, V, nullptr, nullptr, l, out);
}